// Round 7
// baseline (1033.929 us; speedup 1.0000x reference)
//
#include <hip/hip_runtime.h>
#include <math.h>

// GINE GNN: 3x [fused edge-linear + gather + relu + segment-sum] + fused MLP (+head) on MI355X.
// R7: aggregate D=128 restructured — (a) depth-1 software pipeline on the x[src] gathers
//     (ping-pong buffers, 2x-unrolled driver: R6 was latency-stalled at VALUBusy 55%);
//     (b) op_sel channel-packed inner loop: one v_pk_fma_f32 per k with the wave-uniform
//     edge scalar broadcast from the SGPR pair via op_sel — no repack, no horizontal add.

#define BLK 256

typedef __attribute__((ext_vector_type(2))) float f32x2;
typedef __attribute__((ext_vector_type(16))) float f32x16;

// v_pk_fma_f32, wave-uniform src0 in SGPR pair (VOP3P allows 1 sgpr operand).
// lo-broadcast: both result halves use a.lo;  hi-broadcast: both use a.hi.
__device__ inline f32x2 pk_fma_s(f32x2 a_uniform, f32x2 b, f32x2 c) {
    f32x2 d;
    asm("v_pk_fma_f32 %0, %1, %2, %3" : "=v"(d) : "s"(a_uniform), "v"(b), "v"(c));
    return d;
}
__device__ inline f32x2 pk_fma_lo(f32x2 a_uniform, f32x2 b, f32x2 c) {
    f32x2 d;
    asm("v_pk_fma_f32 %0, %1, %2, %3 op_sel:[0,0,0] op_sel_hi:[0,1,1]"
        : "=v"(d) : "s"(a_uniform), "v"(b), "v"(c));
    return d;  // d = {a.lo*b.lo + c.lo, a.lo*b.hi + c.hi}
}
__device__ inline f32x2 pk_fma_hi(f32x2 a_uniform, f32x2 b, f32x2 c) {
    f32x2 d;
    asm("v_pk_fma_f32 %0, %1, %2, %3 op_sel:[1,0,0] op_sel_hi:[1,1,1]"
        : "=v"(d) : "s"(a_uniform), "v"(b), "v"(c));
    return d;  // d = {a.hi*b.lo + c.lo, a.hi*b.hi + c.hi}
}

union EdgeRow {
    f32x16 v;
    f32x2 p[8];
};

// ---------------- CSR build ----------------

// edge_index may be int64 (reference) or int32 (JAX x64 off). int64 LE => odd words all 0.
__global__ void detect_kernel(const unsigned int* __restrict__ ei, int* __restrict__ flag) {
    int t = blockIdx.x * blockDim.x + threadIdx.x;
    if (t < 1024) {
        if (ei[2 * t + 1] != 0u) atomicOr(flag, 1);  // nonzero odd word => int32 mode
    }
}

__global__ void hist_kernel(const void* __restrict__ ei, const int* __restrict__ flag, int E,
                            int* __restrict__ counts) {
    int e = blockIdx.x * blockDim.x + threadIdx.x;
    if (e >= E) return;
    int d = (*flag) ? ((const int*)ei)[E + e] : (int)((const long long*)ei)[E + e];
    atomicAdd(&counts[d], 1);
}

// single-block scan: 256 threads, each owns a contiguous chunk
__global__ void scan_kernel(const int* __restrict__ counts, int* __restrict__ offsets, int n) {
    __shared__ int tsum[256];
    __shared__ int texcl[256];
    int t = threadIdx.x;
    int chunk = (n + 255) >> 8;
    int b = t * chunk, e = min(b + chunk, n);
    int s = 0;
    for (int i = b; i < e; i++) s += counts[i];
    tsum[t] = s;
    __syncthreads();
    if (t == 0) {
        int run = 0;
        for (int i = 0; i < 256; i++) { texcl[i] = run; run += tsum[i]; }
        offsets[n] = run;  // == E
    }
    __syncthreads();
    int run = texcl[t];
    for (int i = b; i < e; i++) { offsets[i] = run; run += counts[i]; }
}

// phase 1: scatter only the 8B {src, eid} record (12.8MB target, L2-friendly)
__global__ void scatter_pos_kernel(const void* __restrict__ ei, const int* __restrict__ flag,
                                   const int* __restrict__ offsets, int* __restrict__ cursor,
                                   int2* __restrict__ meta, int E) {
    int e = blockIdx.x * blockDim.x + threadIdx.x;
    if (e >= E) return;
    int s, d;
    if (*flag) { s = ((const int*)ei)[e]; d = ((const int*)ei)[E + e]; }
    else       { s = (int)((const long long*)ei)[e]; d = (int)((const long long*)ei)[E + e]; }
    int pos = offsets[d] + atomicAdd(&cursor[d], 1);
    meta[pos] = make_int2(s, e);
}

// phase 2: coalesced-write permute; 4 threads per edge (one float4 chunk each)
__global__ void permute_gather_kernel(const int2* __restrict__ meta,
                                      const float4* __restrict__ ea4,
                                      int* __restrict__ srcp, float4* __restrict__ eap4, int E) {
    int t = blockIdx.x * blockDim.x + threadIdx.x;
    if (t >= E * 4) return;
    int pos = t >> 2, c = t & 3;
    int2 m = meta[pos];
    eap4[(size_t)pos * 4 + c] = ea4[(size_t)m.y * 4 + c];
    if (c == 0) srcp[pos] = m.x;
}

// ---------------- fused aggregation, D=128 (C=2) ----------------
// h[node] = x[node] + sum_{e: dst=node} relu( x[src_e] + ea_e @ We + be )
// One wave per node; lane owns 2 channels {c0,c0+1}. Edge row wave-uniform in SGPRs
// (s_load_dwordx16); per k one pk_fma with the edge scalar op_sel-broadcast.
// x-gathers software-pipelined depth 1 (ping-pong xa/xb).
__global__ __launch_bounds__(256) void aggregate128_kernel(
    const float* __restrict__ x, const float* __restrict__ eap,
    const int* __restrict__ srcp,
    const float* __restrict__ We, const float* __restrict__ be,
    const int* __restrict__ offsets,
    float* __restrict__ h, int n) {
    int lane = threadIdx.x & 63;
    int node = __builtin_amdgcn_readfirstlane(blockIdx.x * 4 + (threadIdx.x >> 6));
    if (node >= n) return;
    int c0 = lane * 2;

    // channel-pair weights: wch[k] = {We[k][c0], We[k][c0+1]}  (32 VGPRs, lane-varying)
    f32x2 wch[16];
#pragma unroll
    for (int k = 0; k < 16; k++) wch[k] = *(const f32x2*)(We + k * 128 + c0);
    f32x2 bias2 = *(const f32x2*)(be + c0);
    f32x2 acc2 = *(const f32x2*)(x + (size_t)node * 128 + c0);

    int p = offsets[node], pe = offsets[node + 1];
    int full = (pe - p) >> 2;

    f32x2 xa[4], xb[4];
    auto gather4 = [&](int q, f32x2* xv) {
#pragma unroll
        for (int u = 0; u < 4; u++) {
            int s = srcp[p + q * 4 + u];
            xv[u] = *(const f32x2*)(x + (size_t)s * 128 + c0);
        }
    };
    auto compute4 = [&](int q, const f32x2* xv) {
#pragma unroll
        for (int u = 0; u < 4; u++) {
            EdgeRow er;
            er.v = *(const f32x16*)(eap + (size_t)(p + q * 4 + u) * 16);  // SMEM dwordx16
            f32x2 prod = xv[u] + bias2;
#pragma unroll
            for (int t = 0; t < 8; t++) {
                prod = pk_fma_lo(er.p[t], wch[2 * t], prod);
                prod = pk_fma_hi(er.p[t], wch[2 * t + 1], prod);
            }
            acc2.x += fmaxf(prod.x, 0.f);
            acc2.y += fmaxf(prod.y, 0.f);
        }
    };

    int q = 0;
    if (full > 0) gather4(0, xa);
    for (; q + 2 <= full; q += 2) {
        gather4(q + 1, xb);
        compute4(q, xa);
        if (q + 2 < full) gather4(q + 2, xa);
        compute4(q + 1, xb);
    }
    if (q < full) compute4(q, xa);
    p += full * 4;

    // tail (<= 3 edges)
    for (; p < pe; p++) {
        int s = srcp[p];
        f32x2 xv = *(const f32x2*)(x + (size_t)s * 128 + c0);
        EdgeRow er;
        er.v = *(const f32x16*)(eap + (size_t)p * 16);
        f32x2 prod = xv + bias2;
#pragma unroll
        for (int t = 0; t < 8; t++) {
            prod = pk_fma_lo(er.p[t], wch[2 * t], prod);
            prod = pk_fma_hi(er.p[t], wch[2 * t + 1], prod);
        }
        acc2.x += fmaxf(prod.x, 0.f);
        acc2.y += fmaxf(prod.y, 0.f);
    }
    *(f32x2*)(h + (size_t)node * 128 + c0) = acc2;
}

// ---------------- fused aggregation, D=64 (C=1) ----------------
// k-pair pk_fma with SGPR edge operand + horizontal add; x-gathers pipelined depth 1.
__global__ __launch_bounds__(256) void aggregate64_kernel(
    const float* __restrict__ x, const float* __restrict__ eap,
    const int* __restrict__ srcp,
    const float* __restrict__ We, const float* __restrict__ be,
    const int* __restrict__ offsets,
    float* __restrict__ h, int n) {
    int lane = threadIdx.x & 63;
    int node = __builtin_amdgcn_readfirstlane(blockIdx.x * 4 + (threadIdx.x >> 6));
    if (node >= n) return;
    int c0 = lane;

    f32x2 wp[8];
#pragma unroll
    for (int t = 0; t < 8; t++) {
        f32x2 v; v.x = We[(2 * t) * 64 + c0]; v.y = We[(2 * t + 1) * 64 + c0];
        wp[t] = v;
    }
    float bias = be[c0];
    float acc = x[(size_t)node * 64 + c0];

    int p = offsets[node], pe = offsets[node + 1];
    int full = (pe - p) >> 2;

    float xa[4], xb[4];
    auto gather4 = [&](int q, float* xv) {
#pragma unroll
        for (int u = 0; u < 4; u++) {
            int s = srcp[p + q * 4 + u];
            xv[u] = x[(size_t)s * 64 + c0];
        }
    };
    auto compute4 = [&](int q, const float* xv) {
#pragma unroll
        for (int u = 0; u < 4; u++) {
            EdgeRow er;
            er.v = *(const f32x16*)(eap + (size_t)(p + q * 4 + u) * 16);
            f32x2 prod; prod.x = xv[u] + bias; prod.y = 0.f;
#pragma unroll
            for (int t = 0; t < 8; t++) prod = pk_fma_s(er.p[t], wp[t], prod);
            acc += fmaxf(prod.x + prod.y, 0.f);
        }
    };

    int q = 0;
    if (full > 0) gather4(0, xa);
    for (; q + 2 <= full; q += 2) {
        gather4(q + 1, xb);
        compute4(q, xa);
        if (q + 2 < full) gather4(q + 2, xa);
        compute4(q + 1, xb);
    }
    if (q < full) compute4(q, xa);
    p += full * 4;

    for (; p < pe; p++) {
        int s = srcp[p];
        float xv = x[(size_t)s * 64 + c0];
        EdgeRow er;
        er.v = *(const f32x16*)(eap + (size_t)p * 16);
        f32x2 prod; prod.x = xv + bias; prod.y = 0.f;
#pragma unroll
        for (int t = 0; t < 8; t++) prod = pk_fma_s(er.p[t], wp[t], prod);
        acc += fmaxf(prod.x + prod.y, 0.f);
    }
    h[(size_t)node * 64 + c0] = acc;
}

// ---------------- fused MLP: relu( relu(A@W1+b1) @ W2 + b2 ), optional sigmoid head ----------
// 64-row tile per block; 64x128 intermediate in LDS. HEAD: out[row]=sigmoid(res@Wlin+blin),
// C store skipped (layer-2 output only feeds the head).
template <int K, bool HEAD>
__global__ __launch_bounds__(256) void mlp_kernel(
    const float* __restrict__ A, const float* __restrict__ W1, const float* __restrict__ b1,
    const float* __restrict__ W2, const float* __restrict__ b2,
    float* __restrict__ C, const float* __restrict__ Wlin, const float* __restrict__ blin,
    float* __restrict__ out, int n) {
    __shared__ __align__(16) float As[16][68];    // transposed A tile, padded
    __shared__ __align__(16) float Bs[16][128];   // weight chunk
    __shared__ __align__(16) float Ts[64][132];   // stage-1 result, padded
    int t = threadIdx.x;
    int row0 = blockIdx.x * 64;
    int tr = t >> 5, tc = t & 31;  // rows tr*8..+8, cols tc*4..+4
    float acc[8][4];
#pragma unroll
    for (int r = 0; r < 8; r++)
#pragma unroll
        for (int c = 0; c < 4; c++) acc[r][c] = 0.f;

    int lr = t >> 2, lk = (t & 3) * 4;   // A staging: row lr, k-offset lk
    int bk = t >> 4, bc = (t & 15) * 8;  // B staging

    // ---- stage 1: Ts = relu(A @ W1 + b1) ----
    for (int ks = 0; ks < K; ks += 16) {
        float4 a;
        int grow = row0 + lr;
        if (grow < n) a = *(const float4*)(A + (size_t)grow * K + ks + lk);
        else a = make_float4(0.f, 0.f, 0.f, 0.f);
        As[lk + 0][lr] = a.x; As[lk + 1][lr] = a.y;
        As[lk + 2][lr] = a.z; As[lk + 3][lr] = a.w;

        const float4* bp = (const float4*)(W1 + (size_t)(ks + bk) * 128 + bc);
        float4 b0 = bp[0], b1v = bp[1];
        *(float4*)&Bs[bk][bc] = b0;
        *(float4*)&Bs[bk][bc + 4] = b1v;
        __syncthreads();
#pragma unroll
        for (int kk = 0; kk < 16; kk++) {
            float4 a0 = *(const float4*)&As[kk][tr * 8];
            float4 a1 = *(const float4*)&As[kk][tr * 8 + 4];
            float4 bv = *(const float4*)&Bs[kk][tc * 4];
            float ar[8] = {a0.x, a0.y, a0.z, a0.w, a1.x, a1.y, a1.z, a1.w};
            float bc4[4] = {bv.x, bv.y, bv.z, bv.w};
#pragma unroll
            for (int r = 0; r < 8; r++)
#pragma unroll
                for (int c = 0; c < 4; c++) acc[r][c] = fmaf(ar[r], bc4[c], acc[r][c]);
        }
        __syncthreads();
    }
    {
        float4 bb = *(const float4*)(b1 + tc * 4);
#pragma unroll
        for (int r = 0; r < 8; r++) {
            Ts[tr * 8 + r][tc * 4 + 0] = fmaxf(acc[r][0] + bb.x, 0.f);
            Ts[tr * 8 + r][tc * 4 + 1] = fmaxf(acc[r][1] + bb.y, 0.f);
            Ts[tr * 8 + r][tc * 4 + 2] = fmaxf(acc[r][2] + bb.z, 0.f);
            Ts[tr * 8 + r][tc * 4 + 3] = fmaxf(acc[r][3] + bb.w, 0.f);
        }
    }
    __syncthreads();

    // ---- stage 2: res = relu(Ts @ W2 + b2) ----
#pragma unroll
    for (int r = 0; r < 8; r++)
#pragma unroll
        for (int c = 0; c < 4; c++) acc[r][c] = 0.f;
    for (int ks = 0; ks < 128; ks += 16) {
        const float4* bp = (const float4*)(W2 + (size_t)(ks + bk) * 128 + bc);
        float4 b0 = bp[0], b1v = bp[1];
        *(float4*)&Bs[bk][bc] = b0;
        *(float4*)&Bs[bk][bc + 4] = b1v;
        __syncthreads();
#pragma unroll
        for (int kk = 0; kk < 16; kk++) {
            float4 bv = *(const float4*)&Bs[kk][tc * 4];
            float bc4[4] = {bv.x, bv.y, bv.z, bv.w};
            float ar[8];
#pragma unroll
            for (int r = 0; r < 8; r++) ar[r] = Ts[tr * 8 + r][ks + kk];
#pragma unroll
            for (int r = 0; r < 8; r++)
#pragma unroll
                for (int c = 0; c < 4; c++) acc[r][c] = fmaf(ar[r], bc4[c], acc[r][c]);
        }
        __syncthreads();
    }
    float4 bb = *(const float4*)(b2 + tc * 4);
    if constexpr (HEAD) {
        float4 wl = *(const float4*)(Wlin + tc * 4);
        float bl = *blin;
#pragma unroll
        for (int r = 0; r < 8; r++) {
            float v0 = fmaxf(acc[r][0] + bb.x, 0.f);
            float v1 = fmaxf(acc[r][1] + bb.y, 0.f);
            float v2 = fmaxf(acc[r][2] + bb.z, 0.f);
            float v3 = fmaxf(acc[r][3] + bb.w, 0.f);
            float part = v0 * wl.x + v1 * wl.y + v2 * wl.z + v3 * wl.w;
#pragma unroll
            for (int m = 1; m <= 16; m <<= 1) part += __shfl_xor(part, m, 64);
            int grow = row0 + tr * 8 + r;
            if (tc == 0 && grow < n) out[grow] = 1.f / (1.f + expf(-(part + bl)));
        }
    } else {
#pragma unroll
        for (int r = 0; r < 8; r++) {
            int grow = row0 + tr * 8 + r;
            if (grow < n) {
                float4 v;
                v.x = fmaxf(acc[r][0] + bb.x, 0.f);
                v.y = fmaxf(acc[r][1] + bb.y, 0.f);
                v.z = fmaxf(acc[r][2] + bb.z, 0.f);
                v.w = fmaxf(acc[r][3] + bb.w, 0.f);
                *(float4*)(C + (size_t)grow * 128 + tc * 4) = v;
            }
        }
    }
}

// ---------------- launch ----------------
extern "C" void kernel_launch(void* const* d_in, const int* in_sizes, int n_in,
                              void* d_out, int out_size, void* d_ws, size_t ws_size,
                              hipStream_t stream) {
    const float* x_in = (const float*)d_in[0];
    const void* ei    = d_in[1];
    const float* ea   = (const float*)d_in[2];
    const float* We[3]  = {(const float*)d_in[3], (const float*)d_in[9],  (const float*)d_in[15]};
    const float* be[3]  = {(const float*)d_in[4], (const float*)d_in[10], (const float*)d_in[16]};
    const float* W1[3]  = {(const float*)d_in[5], (const float*)d_in[11], (const float*)d_in[17]};
    const float* b1[3]  = {(const float*)d_in[6], (const float*)d_in[12], (const float*)d_in[18]};
    const float* W2[3]  = {(const float*)d_in[7], (const float*)d_in[13], (const float*)d_in[19]};
    const float* b2[3]  = {(const float*)d_in[8], (const float*)d_in[14], (const float*)d_in[20]};
    const float* Wlin = (const float*)d_in[21];
    const float* blin = (const float*)d_in[22];
    float* out = (float*)d_out;

    const int N = in_sizes[0] / 64;   // 50000
    const int E = in_sizes[1] / 2;    // 1.6M

    size_t off = 0;
    auto alloc = [&](size_t bytes) {
        void* p = (char*)d_ws + off;
        off += (bytes + 255) & ~(size_t)255;
        return p;
    };
    int*   flag    = (int*)alloc(4);
    int*   counts  = (int*)alloc((size_t)N * 4);
    int*   offsets = (int*)alloc((size_t)(N + 1) * 4);
    int*   cursor  = (int*)alloc((size_t)N * 4);
    int2*  meta    = (int2*)alloc((size_t)E * 8);
    int*   srcp    = (int*)alloc((size_t)E * 4);
    float* eap     = (float*)alloc((size_t)E * 16 * 4);
    float* bufA    = (float*)alloc((size_t)N * 128 * 4);
    float* bufC    = (float*)alloc((size_t)N * 128 * 4);

    (void)hipMemsetAsync(flag, 0, 4, stream);
    (void)hipMemsetAsync(counts, 0, (size_t)N * 4, stream);
    (void)hipMemsetAsync(cursor, 0, (size_t)N * 4, stream);

    int egrid = (E + BLK - 1) / BLK;
    detect_kernel<<<4, BLK, 0, stream>>>((const unsigned int*)ei, flag);
    hist_kernel<<<egrid, BLK, 0, stream>>>(ei, flag, E, counts);
    scan_kernel<<<1, BLK, 0, stream>>>(counts, offsets, N);
    scatter_pos_kernel<<<egrid, BLK, 0, stream>>>(ei, flag, offsets, cursor, meta, E);
    permute_gather_kernel<<<(E * 4 + BLK - 1) / BLK, BLK, 0, stream>>>(
        meta, (const float4*)ea, srcp, (float4*)eap, E);

    int ngrid4 = (N + 3) / 4;
    int ggrid  = (N + 63) / 64;

    // layer 0: d=64
    aggregate64_kernel<<<ngrid4, BLK, 0, stream>>>(x_in, eap, srcp, We[0], be[0], offsets, bufA, N);
    mlp_kernel<64, false><<<ggrid, BLK, 0, stream>>>(bufA, W1[0], b1[0], W2[0], b2[0], bufC,
                                                     nullptr, nullptr, nullptr, N);
    // layer 1: d=128
    aggregate128_kernel<<<ngrid4, BLK, 0, stream>>>(bufC, eap, srcp, We[1], be[1], offsets, bufA, N);
    mlp_kernel<128, false><<<ggrid, BLK, 0, stream>>>(bufA, W1[1], b1[1], W2[1], b2[1], bufC,
                                                      nullptr, nullptr, nullptr, N);
    // layer 2: d=128, head fused (sigmoid(res @ Wlin + blin) -> out)
    aggregate128_kernel<<<ngrid4, BLK, 0, stream>>>(bufC, eap, srcp, We[2], be[2], offsets, bufA, N);
    mlp_kernel<128, true><<<ggrid, BLK, 0, stream>>>(bufA, W1[2], b1[2], W2[2], b2[2], nullptr,
                                                     Wlin, blin, out, N);
}

// Round 8
// 997.595 us; speedup vs baseline: 1.0364x; 1.0364x over previous
//
#include <hip/hip_runtime.h>
#include <math.h>

// GINE GNN: 3x [fused edge-linear + gather + relu + segment-sum] + fused MLP (+head) on MI355X.
// R8: aggregate inner loop = two INDEPENDENT 8-deep pk_fma chains (pa: op_sel lo-broadcast,
//     pb: hi-broadcast) merged once — R7 regressed because its single 16-deep dependent chain
//     doubled the critical path (VALUBusy 55->45%). Batch 8 edges/iter with the lean inner
//     (R4's batch-8 failure used the heavy repack inner). Simple rolled loop, no ping-pong.

#define BLK 256

typedef __attribute__((ext_vector_type(2))) float f32x2;
typedef __attribute__((ext_vector_type(16))) float f32x16;

// v_pk_fma_f32, wave-uniform src0 in SGPR pair (VOP3P allows 1 sgpr operand).
__device__ inline f32x2 pk_fma_s(f32x2 a_uniform, f32x2 b, f32x2 c) {
    f32x2 d;
    asm("v_pk_fma_f32 %0, %1, %2, %3" : "=v"(d) : "s"(a_uniform), "v"(b), "v"(c));
    return d;
}
// lo-broadcast: both result halves use a.lo
__device__ inline f32x2 pk_fma_lo(f32x2 a_uniform, f32x2 b, f32x2 c) {
    f32x2 d;
    asm("v_pk_fma_f32 %0, %1, %2, %3 op_sel:[0,0,0] op_sel_hi:[0,1,1]"
        : "=v"(d) : "s"(a_uniform), "v"(b), "v"(c));
    return d;  // d = {a.lo*b.lo + c.lo, a.lo*b.hi + c.hi}
}
// hi-broadcast: both result halves use a.hi
__device__ inline f32x2 pk_fma_hi(f32x2 a_uniform, f32x2 b, f32x2 c) {
    f32x2 d;
    asm("v_pk_fma_f32 %0, %1, %2, %3 op_sel:[1,0,0] op_sel_hi:[1,1,1]"
        : "=v"(d) : "s"(a_uniform), "v"(b), "v"(c));
    return d;  // d = {a.hi*b.lo + c.lo, a.hi*b.hi + c.hi}
}

union EdgeRow {
    f32x16 v;
    f32x2 p[8];
};

// ---------------- CSR build ----------------

// edge_index may be int64 (reference) or int32 (JAX x64 off). int64 LE => odd words all 0.
__global__ void detect_kernel(const unsigned int* __restrict__ ei, int* __restrict__ flag) {
    int t = blockIdx.x * blockDim.x + threadIdx.x;
    if (t < 1024) {
        if (ei[2 * t + 1] != 0u) atomicOr(flag, 1);  // nonzero odd word => int32 mode
    }
}

__global__ void hist_kernel(const void* __restrict__ ei, const int* __restrict__ flag, int E,
                            int* __restrict__ counts) {
    int e = blockIdx.x * blockDim.x + threadIdx.x;
    if (e >= E) return;
    int d = (*flag) ? ((const int*)ei)[E + e] : (int)((const long long*)ei)[E + e];
    atomicAdd(&counts[d], 1);
}

// single-block scan: 256 threads, each owns a contiguous chunk
__global__ void scan_kernel(const int* __restrict__ counts, int* __restrict__ offsets, int n) {
    __shared__ int tsum[256];
    __shared__ int texcl[256];
    int t = threadIdx.x;
    int chunk = (n + 255) >> 8;
    int b = t * chunk, e = min(b + chunk, n);
    int s = 0;
    for (int i = b; i < e; i++) s += counts[i];
    tsum[t] = s;
    __syncthreads();
    if (t == 0) {
        int run = 0;
        for (int i = 0; i < 256; i++) { texcl[i] = run; run += tsum[i]; }
        offsets[n] = run;  // == E
    }
    __syncthreads();
    int run = texcl[t];
    for (int i = b; i < e; i++) { offsets[i] = run; run += counts[i]; }
}

// phase 1: scatter only the 8B {src, eid} record (12.8MB target, L2-friendly)
__global__ void scatter_pos_kernel(const void* __restrict__ ei, const int* __restrict__ flag,
                                   const int* __restrict__ offsets, int* __restrict__ cursor,
                                   int2* __restrict__ meta, int E) {
    int e = blockIdx.x * blockDim.x + threadIdx.x;
    if (e >= E) return;
    int s, d;
    if (*flag) { s = ((const int*)ei)[e]; d = ((const int*)ei)[E + e]; }
    else       { s = (int)((const long long*)ei)[e]; d = (int)((const long long*)ei)[E + e]; }
    int pos = offsets[d] + atomicAdd(&cursor[d], 1);
    meta[pos] = make_int2(s, e);
}

// phase 2: coalesced-write permute; 4 threads per edge (one float4 chunk each)
__global__ void permute_gather_kernel(const int2* __restrict__ meta,
                                      const float4* __restrict__ ea4,
                                      int* __restrict__ srcp, float4* __restrict__ eap4, int E) {
    int t = blockIdx.x * blockDim.x + threadIdx.x;
    if (t >= E * 4) return;
    int pos = t >> 2, c = t & 3;
    int2 m = meta[pos];
    eap4[(size_t)pos * 4 + c] = ea4[(size_t)m.y * 4 + c];
    if (c == 0) srcp[pos] = m.x;
}

// ---------------- fused aggregation, D=128 (C=2) ----------------
// h[node] = x[node] + sum_{e: dst=node} relu( x[src_e] + ea_e @ We + be )
// One wave per node; lane owns channels {c0,c0+1}. Edge row wave-uniform in SGPRs
// (s_load_dwordx16); per k-pair two pk_fma with op_sel broadcast into two INDEPENDENT
// accumulator chains (pa/pb), merged once per edge. Batch 8 edges for gather MLP.
__global__ __launch_bounds__(256) void aggregate128_kernel(
    const float* __restrict__ x, const float* __restrict__ eap,
    const int* __restrict__ srcp,
    const float* __restrict__ We, const float* __restrict__ be,
    const int* __restrict__ offsets,
    float* __restrict__ h, int n) {
    int lane = threadIdx.x & 63;
    int node = __builtin_amdgcn_readfirstlane(blockIdx.x * 4 + (threadIdx.x >> 6));
    if (node >= n) return;
    int c0 = lane * 2;

    // channel-pair weights: wch[k] = {We[k][c0], We[k][c0+1]}  (32 VGPRs, lane-varying)
    f32x2 wch[16];
#pragma unroll
    for (int k = 0; k < 16; k++) wch[k] = *(const f32x2*)(We + k * 128 + c0);
    f32x2 bias2 = *(const f32x2*)(be + c0);
    f32x2 acc2 = *(const f32x2*)(x + (size_t)node * 128 + c0);

    int p = offsets[node], pe = offsets[node + 1];

    // 8 edges per iteration: all 8 x-gathers issued up front (srcp/base scalar, lane offset const)
    for (; p + 8 <= pe; p += 8) {
        f32x2 xv[8];
#pragma unroll
        for (int u = 0; u < 8; u++) {
            int s = srcp[p + u];
            xv[u] = *(const f32x2*)(x + (size_t)s * 128 + c0);
        }
#pragma unroll
        for (int u = 0; u < 8; u++) {
            EdgeRow er;
            er.v = *(const f32x16*)(eap + (size_t)(p + u) * 16);  // wave-uniform -> SMEM
            f32x2 pa = xv[u] + bias2;
            f32x2 pb; pb.x = 0.f; pb.y = 0.f;
#pragma unroll
            for (int t = 0; t < 8; t++) {
                pa = pk_fma_lo(er.p[t], wch[2 * t], pa);      // chain A, depth 8
                pb = pk_fma_hi(er.p[t], wch[2 * t + 1], pb);  // chain B, depth 8 (independent)
            }
            f32x2 pr = pa + pb;
            acc2.x += fmaxf(pr.x, 0.f);
            acc2.y += fmaxf(pr.y, 0.f);
        }
    }
    // tail (<= 7 edges)
    for (; p < pe; p++) {
        int s = srcp[p];
        f32x2 xv = *(const f32x2*)(x + (size_t)s * 128 + c0);
        EdgeRow er;
        er.v = *(const f32x16*)(eap + (size_t)p * 16);
        f32x2 pa = xv + bias2;
        f32x2 pb; pb.x = 0.f; pb.y = 0.f;
#pragma unroll
        for (int t = 0; t < 8; t++) {
            pa = pk_fma_lo(er.p[t], wch[2 * t], pa);
            pb = pk_fma_hi(er.p[t], wch[2 * t + 1], pb);
        }
        f32x2 pr = pa + pb;
        acc2.x += fmaxf(pr.x, 0.f);
        acc2.y += fmaxf(pr.y, 0.f);
    }
    *(f32x2*)(h + (size_t)node * 128 + c0) = acc2;
}

// ---------------- fused aggregation, D=64 (C=1) ----------------
// k-pair pk_fma with SGPR edge operand + horizontal add; batch 8.
__global__ __launch_bounds__(256) void aggregate64_kernel(
    const float* __restrict__ x, const float* __restrict__ eap,
    const int* __restrict__ srcp,
    const float* __restrict__ We, const float* __restrict__ be,
    const int* __restrict__ offsets,
    float* __restrict__ h, int n) {
    int lane = threadIdx.x & 63;
    int node = __builtin_amdgcn_readfirstlane(blockIdx.x * 4 + (threadIdx.x >> 6));
    if (node >= n) return;
    int c0 = lane;

    f32x2 wp[8];
#pragma unroll
    for (int t = 0; t < 8; t++) {
        f32x2 v; v.x = We[(2 * t) * 64 + c0]; v.y = We[(2 * t + 1) * 64 + c0];
        wp[t] = v;
    }
    float bias = be[c0];
    float acc = x[(size_t)node * 64 + c0];

    int p = offsets[node], pe = offsets[node + 1];

    for (; p + 8 <= pe; p += 8) {
        float xv[8];
#pragma unroll
        for (int u = 0; u < 8; u++) {
            int s = srcp[p + u];
            xv[u] = x[(size_t)s * 64 + c0];
        }
#pragma unroll
        for (int u = 0; u < 8; u++) {
            EdgeRow er;
            er.v = *(const f32x16*)(eap + (size_t)(p + u) * 16);
            f32x2 pa; pa.x = xv[u] + bias; pa.y = 0.f;
            f32x2 pb; pb.x = 0.f; pb.y = 0.f;
#pragma unroll
            for (int t = 0; t < 4; t++) {
                pa = pk_fma_s(er.p[2 * t], wp[2 * t], pa);          // chain A
                pb = pk_fma_s(er.p[2 * t + 1], wp[2 * t + 1], pb);  // chain B
            }
            f32x2 pr = pa + pb;
            acc += fmaxf(pr.x + pr.y, 0.f);
        }
    }
    for (; p < pe; p++) {
        int s = srcp[p];
        float xv = x[(size_t)s * 64 + c0];
        EdgeRow er;
        er.v = *(const f32x16*)(eap + (size_t)p * 16);
        f32x2 pa; pa.x = xv + bias; pa.y = 0.f;
        f32x2 pb; pb.x = 0.f; pb.y = 0.f;
#pragma unroll
        for (int t = 0; t < 4; t++) {
            pa = pk_fma_s(er.p[2 * t], wp[2 * t], pa);
            pb = pk_fma_s(er.p[2 * t + 1], wp[2 * t + 1], pb);
        }
        f32x2 pr = pa + pb;
        acc += fmaxf(pr.x + pr.y, 0.f);
    }
    h[(size_t)node * 64 + c0] = acc;
}

// ---------------- fused MLP: relu( relu(A@W1+b1) @ W2 + b2 ), optional sigmoid head ----------
// 64-row tile per block; 64x128 intermediate in LDS. HEAD: out[row]=sigmoid(res@Wlin+blin),
// C store skipped (layer-2 output only feeds the head).
template <int K, bool HEAD>
__global__ __launch_bounds__(256) void mlp_kernel(
    const float* __restrict__ A, const float* __restrict__ W1, const float* __restrict__ b1,
    const float* __restrict__ W2, const float* __restrict__ b2,
    float* __restrict__ C, const float* __restrict__ Wlin, const float* __restrict__ blin,
    float* __restrict__ out, int n) {
    __shared__ __align__(16) float As[16][68];    // transposed A tile, padded
    __shared__ __align__(16) float Bs[16][128];   // weight chunk
    __shared__ __align__(16) float Ts[64][132];   // stage-1 result, padded
    int t = threadIdx.x;
    int row0 = blockIdx.x * 64;
    int tr = t >> 5, tc = t & 31;  // rows tr*8..+8, cols tc*4..+4
    float acc[8][4];
#pragma unroll
    for (int r = 0; r < 8; r++)
#pragma unroll
        for (int c = 0; c < 4; c++) acc[r][c] = 0.f;

    int lr = t >> 2, lk = (t & 3) * 4;   // A staging: row lr, k-offset lk
    int bk = t >> 4, bc = (t & 15) * 8;  // B staging

    // ---- stage 1: Ts = relu(A @ W1 + b1) ----
    for (int ks = 0; ks < K; ks += 16) {
        float4 a;
        int grow = row0 + lr;
        if (grow < n) a = *(const float4*)(A + (size_t)grow * K + ks + lk);
        else a = make_float4(0.f, 0.f, 0.f, 0.f);
        As[lk + 0][lr] = a.x; As[lk + 1][lr] = a.y;
        As[lk + 2][lr] = a.z; As[lk + 3][lr] = a.w;

        const float4* bp = (const float4*)(W1 + (size_t)(ks + bk) * 128 + bc);
        float4 b0 = bp[0], b1v = bp[1];
        *(float4*)&Bs[bk][bc] = b0;
        *(float4*)&Bs[bk][bc + 4] = b1v;
        __syncthreads();
#pragma unroll
        for (int kk = 0; kk < 16; kk++) {
            float4 a0 = *(const float4*)&As[kk][tr * 8];
            float4 a1 = *(const float4*)&As[kk][tr * 8 + 4];
            float4 bv = *(const float4*)&Bs[kk][tc * 4];
            float ar[8] = {a0.x, a0.y, a0.z, a0.w, a1.x, a1.y, a1.z, a1.w};
            float bc4[4] = {bv.x, bv.y, bv.z, bv.w};
#pragma unroll
            for (int r = 0; r < 8; r++)
#pragma unroll
                for (int c = 0; c < 4; c++) acc[r][c] = fmaf(ar[r], bc4[c], acc[r][c]);
        }
        __syncthreads();
    }
    {
        float4 bb = *(const float4*)(b1 + tc * 4);
#pragma unroll
        for (int r = 0; r < 8; r++) {
            Ts[tr * 8 + r][tc * 4 + 0] = fmaxf(acc[r][0] + bb.x, 0.f);
            Ts[tr * 8 + r][tc * 4 + 1] = fmaxf(acc[r][1] + bb.y, 0.f);
            Ts[tr * 8 + r][tc * 4 + 2] = fmaxf(acc[r][2] + bb.z, 0.f);
            Ts[tr * 8 + r][tc * 4 + 3] = fmaxf(acc[r][3] + bb.w, 0.f);
        }
    }
    __syncthreads();

    // ---- stage 2: res = relu(Ts @ W2 + b2) ----
#pragma unroll
    for (int r = 0; r < 8; r++)
#pragma unroll
        for (int c = 0; c < 4; c++) acc[r][c] = 0.f;
    for (int ks = 0; ks < 128; ks += 16) {
        const float4* bp = (const float4*)(W2 + (size_t)(ks + bk) * 128 + bc);
        float4 b0 = bp[0], b1v = bp[1];
        *(float4*)&Bs[bk][bc] = b0;
        *(float4*)&Bs[bk][bc + 4] = b1v;
        __syncthreads();
#pragma unroll
        for (int kk = 0; kk < 16; kk++) {
            float4 bv = *(const float4*)&Bs[kk][tc * 4];
            float bc4[4] = {bv.x, bv.y, bv.z, bv.w};
            float ar[8];
#pragma unroll
            for (int r = 0; r < 8; r++) ar[r] = Ts[tr * 8 + r][ks + kk];
#pragma unroll
            for (int r = 0; r < 8; r++)
#pragma unroll
                for (int c = 0; c < 4; c++) acc[r][c] = fmaf(ar[r], bc4[c], acc[r][c]);
        }
        __syncthreads();
    }
    float4 bb = *(const float4*)(b2 + tc * 4);
    if constexpr (HEAD) {
        float4 wl = *(const float4*)(Wlin + tc * 4);
        float bl = *blin;
#pragma unroll
        for (int r = 0; r < 8; r++) {
            float v0 = fmaxf(acc[r][0] + bb.x, 0.f);
            float v1 = fmaxf(acc[r][1] + bb.y, 0.f);
            float v2 = fmaxf(acc[r][2] + bb.z, 0.f);
            float v3 = fmaxf(acc[r][3] + bb.w, 0.f);
            float part = v0 * wl.x + v1 * wl.y + v2 * wl.z + v3 * wl.w;
#pragma unroll
            for (int m = 1; m <= 16; m <<= 1) part += __shfl_xor(part, m, 64);
            int grow = row0 + tr * 8 + r;
            if (tc == 0 && grow < n) out[grow] = 1.f / (1.f + expf(-(part + bl)));
        }
    } else {
#pragma unroll
        for (int r = 0; r < 8; r++) {
            int grow = row0 + tr * 8 + r;
            if (grow < n) {
                float4 v;
                v.x = fmaxf(acc[r][0] + bb.x, 0.f);
                v.y = fmaxf(acc[r][1] + bb.y, 0.f);
                v.z = fmaxf(acc[r][2] + bb.z, 0.f);
                v.w = fmaxf(acc[r][3] + bb.w, 0.f);
                *(float4*)(C + (size_t)grow * 128 + tc * 4) = v;
            }
        }
    }
}

// ---------------- launch ----------------
extern "C" void kernel_launch(void* const* d_in, const int* in_sizes, int n_in,
                              void* d_out, int out_size, void* d_ws, size_t ws_size,
                              hipStream_t stream) {
    const float* x_in = (const float*)d_in[0];
    const void* ei    = d_in[1];
    const float* ea   = (const float*)d_in[2];
    const float* We[3]  = {(const float*)d_in[3], (const float*)d_in[9],  (const float*)d_in[15]};
    const float* be[3]  = {(const float*)d_in[4], (const float*)d_in[10], (const float*)d_in[16]};
    const float* W1[3]  = {(const float*)d_in[5], (const float*)d_in[11], (const float*)d_in[17]};
    const float* b1[3]  = {(const float*)d_in[6], (const float*)d_in[12], (const float*)d_in[18]};
    const float* W2[3]  = {(const float*)d_in[7], (const float*)d_in[13], (const float*)d_in[19]};
    const float* b2[3]  = {(const float*)d_in[8], (const float*)d_in[14], (const float*)d_in[20]};
    const float* Wlin = (const float*)d_in[21];
    const float* blin = (const float*)d_in[22];
    float* out = (float*)d_out;

    const int N = in_sizes[0] / 64;   // 50000
    const int E = in_sizes[1] / 2;    // 1.6M

    size_t off = 0;
    auto alloc = [&](size_t bytes) {
        void* p = (char*)d_ws + off;
        off += (bytes + 255) & ~(size_t)255;
        return p;
    };
    int*   flag    = (int*)alloc(4);
    int*   counts  = (int*)alloc((size_t)N * 4);
    int*   offsets = (int*)alloc((size_t)(N + 1) * 4);
    int*   cursor  = (int*)alloc((size_t)N * 4);
    int2*  meta    = (int2*)alloc((size_t)E * 8);
    int*   srcp    = (int*)alloc((size_t)E * 4);
    float* eap     = (float*)alloc((size_t)E * 16 * 4);
    float* bufA    = (float*)alloc((size_t)N * 128 * 4);
    float* bufC    = (float*)alloc((size_t)N * 128 * 4);

    (void)hipMemsetAsync(flag, 0, 4, stream);
    (void)hipMemsetAsync(counts, 0, (size_t)N * 4, stream);
    (void)hipMemsetAsync(cursor, 0, (size_t)N * 4, stream);

    int egrid = (E + BLK - 1) / BLK;
    detect_kernel<<<4, BLK, 0, stream>>>((const unsigned int*)ei, flag);
    hist_kernel<<<egrid, BLK, 0, stream>>>(ei, flag, E, counts);
    scan_kernel<<<1, BLK, 0, stream>>>(counts, offsets, N);
    scatter_pos_kernel<<<egrid, BLK, 0, stream>>>(ei, flag, offsets, cursor, meta, E);
    permute_gather_kernel<<<(E * 4 + BLK - 1) / BLK, BLK, 0, stream>>>(
        meta, (const float4*)ea, srcp, (float4*)eap, E);

    int ngrid4 = (N + 3) / 4;
    int ggrid  = (N + 63) / 64;

    // layer 0: d=64
    aggregate64_kernel<<<ngrid4, BLK, 0, stream>>>(x_in, eap, srcp, We[0], be[0], offsets, bufA, N);
    mlp_kernel<64, false><<<ggrid, BLK, 0, stream>>>(bufA, W1[0], b1[0], W2[0], b2[0], bufC,
                                                     nullptr, nullptr, nullptr, N);
    // layer 1: d=128
    aggregate128_kernel<<<ngrid4, BLK, 0, stream>>>(bufC, eap, srcp, We[1], be[1], offsets, bufA, N);
    mlp_kernel<128, false><<<ggrid, BLK, 0, stream>>>(bufA, W1[1], b1[1], W2[1], b2[1], bufC,
                                                      nullptr, nullptr, nullptr, N);
    // layer 2: d=128, head fused (sigmoid(res @ Wlin + blin) -> out)
    aggregate128_kernel<<<ngrid4, BLK, 0, stream>>>(bufC, eap, srcp, We[2], be[2], offsets, bufA, N);
    mlp_kernel<128, true><<<ggrid, BLK, 0, stream>>>(bufA, W1[2], b1[2], W2[2], b2[2], nullptr,
                                                     Wlin, blin, out, N);
}